// Round 6
// baseline (550.857 us; speedup 1.0000x reference)
//
#include <hip/hip_runtime.h>

typedef unsigned short u16;
typedef __attribute__((ext_vector_type(8))) __bf16 bf8_t;
typedef __attribute__((ext_vector_type(4))) float f4_t;

union bf8u { u16 u[8]; bf8_t v; uint4 q; };

// ---------- bf16 helpers ----------
__device__ __forceinline__ float bf2f(u16 v) {
  return __uint_as_float(((unsigned int)v) << 16);
}
__device__ __forceinline__ u16 f2bf(float f) {
  union { __bf16 h; u16 u; } c;          // gfx950: single v_cvt_pk_bf16_f32 (RNE)
  c.h = (__bf16)f;
  return c.u;
}
__device__ __forceinline__ float bflo(unsigned int w) { return __uint_as_float(w << 16); }
__device__ __forceinline__ float bfhi(unsigned int w) { return __uint_as_float(w & 0xFFFF0000u); }
__device__ __forceinline__ float ldf1(const void* p, size_t i, int isf32) {
  return isf32 ? ((const float*)p)[i] : bf2f(((const u16*)p)[i]);
}

// ---------- sizes ----------
#define LQ    2500
#define LQP   2560      /* padded token count for Vt */
#define BB    2
#define CC    256
#define NCC   6
#define HFF   64
#define WFF   176
#define DFF   1024
#define MROWS 5000

// ---------- workspace byte offsets (end < 20.7MB proven-safe) ----------
#define WB_UV   256
#define WB_WQKV 240256
#define WB_WOP  633472
#define WB_WSC  764544
#define WB_WF1  895616
#define WB_WF2  1419904
#define WB_S1   1944192                 /* 2,621,440 each */
#define WB_S2   (WB_S1 + 2621440)
#define WB_S3   (WB_S2 + 2621440)
#define WB_VT   (WB_S3 + 2621440)       /* 512 x 2560 x 2B */
#define WB_H    WB_S2                   /* overlaps S2,S3,VT (dead at FFN time) */
#define WB_Y3   (WB_S2 + 10485760)
#define WB_XQ   WB_Y3                   /* bf16 bevq; overlaps Y3 (dead until FFN2; XQ dead after QKV) */
#define WB_XKV  (WB_Y3 + 2621440)       /* bf16 prev_bev; end 20,232,832 < 20.7MB */

// ============================================================
__global__ void detect_k(const u16* __restrict__ rp, int* __restrict__ flag) {
  int bad = 0;
  for (int i = threadIdx.x; i < 7500; i += 64) {
    float v = bf2f(rp[i]);
    if (!(fabsf(v) < 1e6f)) bad = 1;
  }
  int anybad = __any(bad);
  if (threadIdx.x == 0) flag[0] = anybad ? 1 : 0;   // 1 = f32, 0 = bf16
}

// ============================================================
// weight/activation prep: convert / transpose / zero-fill into bf16 ws
//   mode 0: scalar convert       mode 1: transpose convert
//   mode 2: zero Vt pad          mode 3: vectorized x4 convert (n in groups of 4)
// ============================================================
struct WDesc {
  const void* src[8];
  u16* dst[8];
  int n[8];
  int mode[8];
  int Kd[8], Nd[8];
};
__global__ __launch_bounds__(256) void cvtw_k(WDesc d, const int* __restrict__ flag) {
  const int df = flag[0];
  const int i = blockIdx.y;
  const int n = d.n[i];
  for (int j = blockIdx.x * 256 + threadIdx.x; j < n; j += gridDim.x * 256) {
    if (d.mode[i] == 3) {
      if (df) {
        const float4 r = ((const float4*)d.src[i])[j];
        const unsigned int lo = (unsigned int)f2bf(r.x) | ((unsigned int)f2bf(r.y) << 16);
        const unsigned int hi = (unsigned int)f2bf(r.z) | ((unsigned int)f2bf(r.w) << 16);
        ((uint2*)d.dst[i])[j] = make_uint2(lo, hi);
      } else {
        ((uint2*)d.dst[i])[j] = ((const uint2*)d.src[i])[j];
      }
    } else if (d.mode[i] == 2) {
      const int row = j / (LQP - LQ), col = LQ + j % (LQP - LQ);
      d.dst[i][(size_t)row * LQP + col] = 0;
    } else if (d.mode[i] == 1) {
      const int K = d.Kd[i], N = d.Nd[i];
      const int nn = j / K, kk = j - nn * K;
      d.dst[i][j] = f2bf(ldf1(d.src[i], (size_t)kk * N + nn, df));
    } else {
      d.dst[i][j] = f2bf(ldf1(d.src[i], j, df));
    }
  }
}

// ============================================================
// Tiled 128x128 MFMA GEMM, 4 waves (2x2), LDS-staged A and B.
//   Per K-step(32): stage A[128][32]+B[128][32] (reg-prefetched
//   uint4 loads -> ds_write_b128), each wave 4+4 ds_read_b128 frags,
//   16 MFMA.  B read from L2 once per 128-row block (8x less B
//   traffic than the old per-16-row-wave structure) and 2x MFMA:load.
//   LDS rows padded to 40 u16 (80B): bank = (20*row)%32 -> 2-way max.
//   QKV=1: N=768 fused projection; n-tile selects input (Q: Xa,
//   K/V: Xb) and output routing (V stored transposed+perm6 for attn).
// ============================================================
#define LDP 40
template<int KT, int ACT, int RES, int QKV>
__global__ __launch_bounds__(256) void gemm_t(
    const u16* __restrict__ Xa, const u16* __restrict__ Xb,
    const u16* __restrict__ W, const void* __restrict__ bias, size_t boff,
    const void* __restrict__ resv,
    u16* __restrict__ Y, u16* __restrict__ Yk, u16* __restrict__ Yv,
    int M, int N, const int* __restrict__ flag)
{
  __shared__ __align__(16) u16 sA[128 * LDP];
  __shared__ __align__(16) u16 sB[128 * LDP];
  const int df = flag[0];
  const int t = threadIdx.x;
  const int lane = t & 63, w = t >> 6;
  const int ln15 = lane & 15, l4 = lane >> 4;
  const int wm = w & 1, wn = w >> 1;
  const int m0 = blockIdx.x * 128, n0 = blockIdx.y * 128;
  const u16* X = (QKV && n0 >= 256) ? Xb : Xa;

  // staging map: thread t covers rows r0 and r0+64, 16B segment seg
  const int r0 = t >> 2, seg = t & 3;
  const int gr0 = min(m0 + r0, M - 1);
  const int gr1 = min(m0 + r0 + 64, M - 1);
  const u16* Asrc0 = X + (size_t)gr0 * KT + seg * 8;
  const u16* Asrc1 = X + (size_t)gr1 * KT + seg * 8;
  const u16* Bsrc0 = W + (size_t)(n0 + r0) * KT + seg * 8;
  const u16* Bsrc1 = W + (size_t)(n0 + r0 + 64) * KT + seg * 8;
  u16* Adst0 = &sA[r0 * LDP + seg * 8];
  u16* Adst1 = &sA[(r0 + 64) * LDP + seg * 8];
  u16* Bdst0 = &sB[r0 * LDP + seg * 8];
  u16* Bdst1 = &sB[(r0 + 64) * LDP + seg * 8];

  f4_t acc[4][4];
#pragma unroll
  for (int mi = 0; mi < 4; ++mi)
#pragma unroll
    for (int ni = 0; ni < 4; ++ni) acc[mi][ni] = (f4_t){0.f, 0.f, 0.f, 0.f};

  uint4 ra0 = *(const uint4*)Asrc0;
  uint4 ra1 = *(const uint4*)Asrc1;
  uint4 rb0 = *(const uint4*)Bsrc0;
  uint4 rb1 = *(const uint4*)Bsrc1;

  for (int k0 = 0; k0 < KT; k0 += 32) {
    __syncthreads();                    // previous step's frag reads done
    *(uint4*)Adst0 = ra0;  *(uint4*)Adst1 = ra1;
    *(uint4*)Bdst0 = rb0;  *(uint4*)Bdst1 = rb1;
    __syncthreads();
    bf8u a[4], b[4];
#pragma unroll
    for (int mi = 0; mi < 4; ++mi)
      a[mi].q = *(const uint4*)&sA[(wm * 64 + mi * 16 + ln15) * LDP + l4 * 8];
#pragma unroll
    for (int ni = 0; ni < 4; ++ni)
      b[ni].q = *(const uint4*)&sB[(wn * 64 + ni * 16 + ln15) * LDP + l4 * 8];
    if (k0 + 32 < KT) {                 // prefetch next step under MFMA
      ra0 = *(const uint4*)(Asrc0 + k0 + 32);
      ra1 = *(const uint4*)(Asrc1 + k0 + 32);
      rb0 = *(const uint4*)(Bsrc0 + k0 + 32);
      rb1 = *(const uint4*)(Bsrc1 + k0 + 32);
    }
#pragma unroll
    for (int mi = 0; mi < 4; ++mi)
#pragma unroll
      for (int ni = 0; ni < 4; ++ni)
        acc[mi][ni] = __builtin_amdgcn_mfma_f32_16x16x32_bf16(a[mi].v, b[ni].v, acc[mi][ni], 0, 0, 0);
  }

#pragma unroll
  for (int ni = 0; ni < 4; ++ni) {
    const int gn = n0 + wn * 64 + ni * 16 + ln15;
    const float bv = ldf1(bias, boff + gn, df);
#pragma unroll
    for (int mi = 0; mi < 4; ++mi) {
#pragma unroll
      for (int r = 0; r < 4; ++r) {
        const int gm = m0 + wm * 64 + mi * 16 + l4 * 4 + r;
        if (gm < M) {
          float x = acc[mi][ni][r] + bv;
          if (ACT) x = 0.5f * x * (1.f + erff(x * 0.70710678118654752f));
          if (RES == 1)      x += bf2f(((const u16*)resv)[(size_t)gm * N + gn]);
          else if (RES == 2) x += ldf1(resv, (size_t)gm * N + gn, df);
          if (QKV) {
            const int which = n0 >> 8;          // block-uniform: 0=Q 1=K 2=V
            const int cn = gn & 255;
            if (which == 2) {
              const int tt = gm >> 1, tx = tt & 63;
              const int tp = (tx & 35) | ((tx & 12) << 1) | ((tx & 16) >> 2);
              Yv[(size_t)(cn + (gm & 1) * 256) * LQP + ((tt & ~63) | tp)] = f2bf(x);
            } else if (which == 1) {
              Yk[(size_t)gm * 256 + cn] = f2bf(x);
            } else {
              Y[(size_t)gm * 256 + cn] = f2bf(x);
            }
          } else {
            Y[(size_t)gm * N + gn] = f2bf(x);
          }
        }
      }
    }
  }
}

// ============================================================
// Split-K flash attention, swapped-operand + register-resident P.
// (unchanged from R4: K-prefetch, defer-max, setprio — verified equal)
// ============================================================
#define TPW 10
__global__ __launch_bounds__(256) void attn_mf(
    const u16* __restrict__ Qw, const u16* __restrict__ Kw,
    const u16* __restrict__ Vt, u16* __restrict__ Ow)
{
  __shared__ float sO[4][16][33];                // [wave][q][32 d + pad]
  __shared__ float sM[4][16];
  __shared__ float sL[4][16];
  const int t = threadIdx.x;
  const int lane = t & 63, w = t >> 6;
  const int ln15 = lane & 15, l4 = lane >> 4;
  const int q0 = blockIdx.x * 16;
  const int by = blockIdx.y;           // b*8+h
  const int b = by >> 3, h = by & 7;
  const float SCL2E = 0.25505654481f;  // (1/sqrt(32)) * log2(e)

  bf8u aq;
  {
    const int qrow = min(q0 + ln15, LQ - 1);
    bf8u qr; qr.q = *(const uint4*)&Qw[((size_t)qrow * BB + b) * CC + h * 32 + l4 * 8];
#pragma unroll
    for (int i = 0; i < 8; ++i) aq.u[i] = f2bf(bf2f(qr.u[i]) * SCL2E);
  }

  f4_t oacc[2];                        // oacc[dt][r] = O^T[d = dt*16+l4*4+r][q = ln15]
  oacc[0] = (f4_t){0.f,0.f,0.f,0.f};
  oacc[1] = (f4_t){0.f,0.f,0.f,0.f};
  float m_r = -1e30f;
  float l_r = 0.f;                     // per-lane partial (16 of 64 keys/tile)

  const int kt0 = w * TPW;
  const u16* Kbase = &Kw[(size_t)b * CC + h * 32 + l4 * 8];
  const u16* Vbase = &Vt[(size_t)(by * 32 + ln15) * LQP + l4 * 8];

  // ---- prefetch K for first tile ----
  bf8u bkn[4];
#pragma unroll
  for (int nt = 0; nt < 4; ++nt)
    bkn[nt].q = *(const uint4*)&Kbase[(size_t)(kt0 * 64 + nt * 16 + ln15) * CC];

  for (int kt = kt0; kt < kt0 + TPW; ++kt) {
    const int kb = kt * 64;
    // ---- Vt loads (consumed last): latency hides under QK+softmax ----
    bf8u av[2][2];
#pragma unroll
    for (int m = 0; m < 2; ++m)
#pragma unroll
      for (int dt = 0; dt < 2; ++dt)
        av[m][dt].q = *(const uint4*)&Vbase[(size_t)(dt * 16) * LQP + kb + m * 32];
    // ---- consume prefetched K; issue next tile's K loads ----
    bf8u bk[4];
#pragma unroll
    for (int nt = 0; nt < 4; ++nt) bk[nt] = bkn[nt];
    if (kt + 1 < kt0 + TPW) {
#pragma unroll
      for (int nt = 0; nt < 4; ++nt)
        bkn[nt].q = *(const uint4*)&Kbase[(size_t)(kb + 64 + nt * 16 + ln15) * CC];
    }
    f4_t sv[4];
    __builtin_amdgcn_s_setprio(1);
#pragma unroll
    for (int nt = 0; nt < 4; ++nt) {
      f4_t z = (f4_t){0.f,0.f,0.f,0.f};
      sv[nt] = __builtin_amdgcn_mfma_f32_16x16x32_bf16(bk[nt].v, aq.v, z, 0, 0, 0);
    }
    __builtin_amdgcn_s_setprio(0);
    float p[4][4];
    if (kb + 64 <= LQ) {
#pragma unroll
      for (int nt = 0; nt < 4; ++nt)
#pragma unroll
        for (int r = 0; r < 4; ++r) p[nt][r] = sv[nt][r];
    } else {
#pragma unroll
      for (int nt = 0; nt < 4; ++nt)
#pragma unroll
        for (int r = 0; r < 4; ++r)
          p[nt][r] = (kb + nt * 16 + l4 * 4 + r < LQ) ? sv[nt][r] : -1e30f;
    }
    // ---- softmax: lane owns one q-row (16 of this tile's 64 keys) ----
    const float m0 = fmaxf(fmaxf(p[0][0], p[0][1]), fmaxf(p[0][2], p[0][3]));
    const float m1 = fmaxf(fmaxf(p[1][0], p[1][1]), fmaxf(p[1][2], p[1][3]));
    const float m2 = fmaxf(fmaxf(p[2][0], p[2][1]), fmaxf(p[2][2], p[2][3]));
    const float m3 = fmaxf(fmaxf(p[3][0], p[3][1]), fmaxf(p[3][2], p[3][3]));
    float mloc = fmaxf(fmaxf(m0, m1), fmaxf(m2, m3));
    mloc = fmaxf(mloc, __shfl_xor(mloc, 16));
    mloc = fmaxf(mloc, __shfl_xor(mloc, 32));
    // ---- defer-max: only rescale when some row grew by > 8 (2^8 bound) ----
    if (__any(mloc > m_r + 8.f)) {
      const float mn = fmaxf(m_r, mloc);      // per-lane, q-consistent
      const float alpha = __builtin_amdgcn_exp2f(m_r - mn);
      m_r = mn;
      l_r *= alpha;
#pragma unroll
      for (int r = 0; r < 4; ++r) { oacc[0][r] *= alpha; oacc[1][r] *= alpha; }
    }
    float s = 0.f;
#pragma unroll
    for (int nt = 0; nt < 4; ++nt) {
#pragma unroll
      for (int r = 0; r < 4; ++r) {
        const float e = __builtin_amdgcn_exp2f(p[nt][r] - m_r);
        p[nt][r] = e; s += e;
      }
    }
    l_r += s;
    // ---- PV with register-resident P (permuted virtual k-slots) ----
    __builtin_amdgcn_s_setprio(1);
#pragma unroll
    for (int m = 0; m < 2; ++m) {
      bf8u pb;                        // slot i -> key (2m+(i>>2))*16 + l4*4 + (i&3)
#pragma unroll
      for (int i = 0; i < 8; ++i) pb.u[i] = f2bf(p[2 * m + (i >> 2)][i & 3]);
#pragma unroll
      for (int dt = 0; dt < 2; ++dt)
        oacc[dt] = __builtin_amdgcn_mfma_f32_16x16x32_bf16(av[m][dt].v, pb.v, oacc[dt], 0, 0, 0);
    }
    __builtin_amdgcn_s_setprio(0);
  }
  // ---- reduce l across the 4 l4-lanes of each q (consistent scaling) ----
  l_r += __shfl_xor(l_r, 16);
  l_r += __shfl_xor(l_r, 32);
  // ---- write partials, merge in LDS ----
#pragma unroll
  for (int dt = 0; dt < 2; ++dt)
#pragma unroll
    for (int r = 0; r < 4; ++r)
      sO[w][ln15][dt * 16 + l4 * 4 + r] = oacc[dt][r];
  if (l4 == 0) { sM[w][ln15] = m_r; sL[w][ln15] = l_r; }
  __syncthreads();
#pragma unroll
  for (int i = t; i < 512; i += 256) {
    const int row = i >> 5, col = i & 31;
    const float M = fmaxf(fmaxf(sM[0][row], sM[1][row]), fmaxf(sM[2][row], sM[3][row]));
    float l = 0.f, O = 0.f;
#pragma unroll
    for (int w4 = 0; w4 < 4; ++w4) {
      const float sc = __builtin_amdgcn_exp2f(sM[w4][row] - M);
      l += sc * sL[w4][row];
      O += sc * sO[w4][row][col];
    }
    const int q = q0 + row;
    if (q < LQ)
      Ow[((size_t)q * BB + b) * CC + h * 32 + col] = f2bf(O / l);
  }
}

// ============================================================
// LayerNorm over C=256; one wave per row; 4 rows per block.
// ============================================================
template<int TOOUT>
__global__ __launch_bounds__(256) void ln_k(const u16* __restrict__ X,
    const void* __restrict__ g, const void* __restrict__ be,
    void* __restrict__ Yv, int rows, const int* __restrict__ flag)
{
  const int df = flag[0];
  const int lane = threadIdx.x & 63;
  const int row = blockIdx.x * 4 + (threadIdx.x >> 6);
  if (row >= rows) return;
  uint2 raw = *(const uint2*)(X + (size_t)row * CC + lane * 4);
  float vx = bflo(raw.x), vy = bfhi(raw.x), vz = bflo(raw.y), vw = bfhi(raw.y);
  float s = vx + vy + vz + vw;
#pragma unroll
  for (int o = 1; o < 64; o <<= 1) s += __shfl_xor(s, o);
  const float mean = s * 0.00390625f;
  const float dx = vx - mean, dy = vy - mean, dz = vz - mean, dw = vw - mean;
  float sq = dx*dx + dy*dy + dz*dz + dw*dw;
#pragma unroll
  for (int o = 1; o < 64; o <<= 1) sq += __shfl_xor(sq, o);
  const float rstd = rsqrtf(sq * 0.00390625f + 1e-5f);
  const float g0 = ldf1(g, lane*4+0, df), g1 = ldf1(g, lane*4+1, df);
  const float g2 = ldf1(g, lane*4+2, df), g3 = ldf1(g, lane*4+3, df);
  const float b0 = ldf1(be, lane*4+0, df), b1 = ldf1(be, lane*4+1, df);
  const float b2 = ldf1(be, lane*4+2, df), b3 = ldf1(be, lane*4+3, df);
  const float y0 = dx * rstd * g0 + b0;
  const float y1 = dy * rstd * g1 + b1;
  const float y2 = dz * rstd * g2 + b2;
  const float y3 = dw * rstd * g3 + b3;
  if (TOOUT && df) {
    float* yp = (float*)Yv + (size_t)row * CC + lane * 4;
    *(float4*)yp = make_float4(y0, y1, y2, y3);
  } else {
    u16* yp = (u16*)Yv + (size_t)row * CC + lane * 4;
    unsigned int lo = (unsigned int)f2bf(y0) | ((unsigned int)f2bf(y1) << 16);
    unsigned int hi = (unsigned int)f2bf(y2) | ((unsigned int)f2bf(y3) << 16);
    *(uint2*)yp = make_uint2(lo, hi);
  }
}

// ============================================================
__global__ __launch_bounds__(256) void uv_k(
    const void* __restrict__ refp, const void* __restrict__ intr,
    const void* __restrict__ extr, float* __restrict__ uv,
    const int* __restrict__ flag)
{
  const int df = flag[0];
  const int idx = blockIdx.x * 256 + threadIdx.x;
  if (idx >= BB * NCC * LQ) return;
  const int bc = idx / LQ;
  const int q = idx - bc * LQ;
  float R[3][3], tv[3], Kc[3][3], p[3];
#pragma unroll
  for (int i = 0; i < 3; ++i) {
#pragma unroll
    for (int j = 0; j < 3; ++j) {
      R[i][j] = ldf1(extr, bc*16 + i*4 + j, df);
      Kc[i][j] = ldf1(intr, bc*9 + i*3 + j, df);
    }
    tv[i] = ldf1(extr, bc*16 + i*4 + 3, df);
  }
#pragma unroll
  for (int j = 0; j < 3; ++j) p[j] = ldf1(refp, q*3 + j, df) - tv[j];
  float pc[3];
#pragma unroll
  for (int i = 0; i < 3; ++i) pc[i] = R[0][i]*p[0] + R[1][i]*p[1] + R[2][i]*p[2];
  float im[3];
#pragma unroll
  for (int i = 0; i < 3; ++i) im[i] = Kc[i][0]*pc[0] + Kc[i][1]*pc[1] + Kc[i][2]*pc[2];
  const float z = fmaxf(im[2], 1e-5f);
  uv[(size_t)idx*2 + 0] = im[0] / z - 0.5f;
  uv[(size_t)idx*2 + 1] = im[1] / z - 0.5f;
}

// ============================================================
// Grid-sample (R0-R4 proven version).
// ============================================================
__global__ __launch_bounds__(256) void samp_k(
    const void* __restrict__ feat, const float* __restrict__ uv,
    u16* __restrict__ S, const int* __restrict__ flag)
{
  const int df = flag[0];
  const int c = blockIdx.x;
  const int b = blockIdx.y / 5;
  const int ch = blockIdx.y % 5;
  const int qend = min((ch + 1) * 500, LQ);
  for (int q = ch * 500 + threadIdx.x; q < qend; q += 256) {
    float acc = 0.f;
#pragma unroll
    for (int cam = 0; cam < NCC; ++cam) {
      const int bc = b * NCC + cam;
      const float x = uv[((size_t)bc * LQ + q) * 2 + 0];
      const float y = uv[((size_t)bc * LQ + q) * 2 + 1];
      const float xf = floorf(x), yf = floorf(y);
      const int x0 = (int)xf, y0 = (int)yf;
      const float wx = x - xf, wy = y - yf;
      const size_t base = ((size_t)bc * CC + c) * (HFF * WFF);
      const bool vx0 = (x0 >= 0) & (x0 < WFF);
      const bool vx1 = (x0 + 1 >= 0) & (x0 + 1 < WFF);
      const bool vy0 = (y0 >= 0) & (y0 < HFF);
      const bool vy1 = (y0 + 1 >= 0) & (y0 + 1 < HFF);
      if (vy0) {
        const size_t rb = base + (size_t)y0 * WFF;
        if (vx0) acc += (1.f - wx) * (1.f - wy) * ldf1(feat, rb + x0, df);
        if (vx1) acc += wx * (1.f - wy) * ldf1(feat, rb + x0 + 1, df);
      }
      if (vy1) {
        const size_t rb = base + (size_t)(y0 + 1) * WFF;
        if (vx0) acc += (1.f - wx) * wy * ldf1(feat, rb + x0, df);
        if (vx1) acc += wx * wy * ldf1(feat, rb + x0 + 1, df);
      }
    }
    S[((size_t)q * BB + b) * CC + c] = f2bf(acc * (1.f / 6.f));
  }
}

// ============================================================
extern "C" void kernel_launch(void* const* d_in, const int* in_sizes, int n_in,
                              void* d_out, int out_size, void* d_ws, size_t ws_size,
                              hipStream_t stream) {
  (void)in_sizes; (void)n_in; (void)out_size; (void)ws_size;
  char* base = (char*)d_ws;
  int* flag = (int*)base;
  float* UV = (float*)(base + WB_UV);
  u16* WQKV = (u16*)(base + WB_WQKV);
  u16* WOP  = (u16*)(base + WB_WOP);
  u16* WSC  = (u16*)(base + WB_WSC);
  u16* WF1  = (u16*)(base + WB_WF1);
  u16* WF2  = (u16*)(base + WB_WF2);
  u16* S1 = (u16*)(base + WB_S1);
  u16* S2 = (u16*)(base + WB_S2);
  u16* S3 = (u16*)(base + WB_S3);
  u16* VT = (u16*)(base + WB_VT);
  u16* H  = (u16*)(base + WB_H);
  u16* Y3 = (u16*)(base + WB_Y3);
  u16* XQ  = (u16*)(base + WB_XQ);
  u16* XKV = (u16*)(base + WB_XKV);

  detect_k<<<1, 64, 0, stream>>>((const u16*)d_in[3], flag);

  WDesc wd;
  wd.src[0] = d_in[7];  wd.dst[0] = WQKV; wd.n[0] = 49152;  wd.mode[0] = 3; wd.Kd[0] = 0;    wd.Nd[0] = 0;
  wd.src[1] = d_in[9];  wd.dst[1] = WOP;  wd.n[1] = 16384;  wd.mode[1] = 3; wd.Kd[1] = 0;    wd.Nd[1] = 0;
  wd.src[2] = d_in[13]; wd.dst[2] = WSC;  wd.n[2] = 16384;  wd.mode[2] = 3; wd.Kd[2] = 0;    wd.Nd[2] = 0;
  wd.src[3] = d_in[17]; wd.dst[3] = WF1;  wd.n[3] = 262144; wd.mode[3] = 1; wd.Kd[3] = 256;  wd.Nd[3] = 1024;
  wd.src[4] = d_in[19]; wd.dst[4] = WF2;  wd.n[4] = 262144; wd.mode[4] = 1; wd.Kd[4] = 1024; wd.Nd[4] = 256;
  wd.src[5] = nullptr;  wd.dst[5] = VT;   wd.n[5] = 512 * (LQP - LQ); wd.mode[5] = 2; wd.Kd[5] = 0; wd.Nd[5] = 0;
  wd.src[6] = d_in[0];  wd.dst[6] = XQ;   wd.n[6] = 320000; wd.mode[6] = 3; wd.Kd[6] = 0;    wd.Nd[6] = 0;
  wd.src[7] = d_in[1];  wd.dst[7] = XKV;  wd.n[7] = 320000; wd.mode[7] = 3; wd.Kd[7] = 0;    wd.Nd[7] = 0;
  cvtw_k<<<dim3(128, 8), 256, 0, stream>>>(wd, flag);

  uv_k<<<(BB * NCC * LQ + 255) / 256, 256, 0, stream>>>(d_in[3], d_in[4], d_in[5], UV, flag);

  // Fused QKV projection (tiled): Q->S1, K->S2, V->VT (perm store)
  gemm_t<256,0,0,1><<<dim3(40, 6), 256, 0, stream>>>(XQ, XKV, WQKV, d_in[8], 0, nullptr, S1, S2, VT, MROWS, 768, flag);

  attn_mf<<<dim3(157, 16), 256, 0, stream>>>(S1, S2, VT, S3);

  // out-proj (+bevq residual) -> S1, LN1 -> S2
  gemm_t<256,0,2,0><<<dim3(40, 2), 256, 0, stream>>>(S3, nullptr, WOP, d_in[10], 0, d_in[0], S1, nullptr, nullptr, MROWS, CC, flag);
  ln_k<0><<<1250, 256, 0, stream>>>(S1, d_in[11], d_in[12], S2, MROWS, flag);

  // sampling -> VT slot (dead after attn)
  samp_k<<<dim3(CC, BB * 5), 256, 0, stream>>>(d_in[2], UV, VT, flag);

  // SCA (+S2 residual) -> S3, LN2 -> S1
  gemm_t<256,0,1,0><<<dim3(40, 2), 256, 0, stream>>>(VT, nullptr, WSC, d_in[14], 0, S2, S3, nullptr, nullptr, MROWS, CC, flag);
  ln_k<0><<<1250, 256, 0, stream>>>(S3, d_in[15], d_in[16], S1, MROWS, flag);

  // FFN: gelu(S1 @ W1 + b1) -> H ; H @ W2 + b2 + S1 -> Y3 ; LN3 -> out
  gemm_t<256,1,0,0><<<dim3(40, 8), 256, 0, stream>>>(S1, nullptr, WF1, d_in[18], 0, nullptr, H, nullptr, nullptr, MROWS, DFF, flag);
  gemm_t<1024,0,1,0><<<dim3(40, 2), 256, 0, stream>>>(H, nullptr, WF2, d_in[20], 0, S1, Y3, nullptr, nullptr, MROWS, CC, flag);
  ln_k<1><<<1250, 256, 0, stream>>>(Y3, d_in[21], d_in[22], d_out, MROWS, flag);
}

// Round 7
// 503.659 us; speedup vs baseline: 1.0937x; 1.0937x over previous
//
#include <hip/hip_runtime.h>

typedef unsigned short u16;
typedef __attribute__((ext_vector_type(8))) __bf16 bf8_t;
typedef __attribute__((ext_vector_type(4))) float f4_t;

union bf8u { u16 u[8]; bf8_t v; uint4 q; };

// ---------- bf16 helpers ----------
__device__ __forceinline__ float bf2f(u16 v) {
  return __uint_as_float(((unsigned int)v) << 16);
}
__device__ __forceinline__ u16 f2bf(float f) {
  union { __bf16 h; u16 u; } c;          // gfx950: single v_cvt_pk_bf16_f32 (RNE)
  c.h = (__bf16)f;
  return c.u;
}
__device__ __forceinline__ float bflo(unsigned int w) { return __uint_as_float(w << 16); }
__device__ __forceinline__ float bfhi(unsigned int w) { return __uint_as_float(w & 0xFFFF0000u); }
__device__ __forceinline__ float ldf1(const void* p, size_t i, int isf32) {
  return isf32 ? ((const float*)p)[i] : bf2f(((const u16*)p)[i]);
}

// ---------- sizes ----------
#define LQ    2500
#define LQP   2560      /* padded token count for Vt */
#define BB    2
#define CC    256
#define NCC   6
#define HFF   64
#define WFF   176
#define DFF   1024
#define MROWS 5000

// ---------- workspace byte offsets (end < 20.7MB proven-safe) ----------
#define WB_UV   256
#define WB_WQKV 240256
#define WB_WOP  633472
#define WB_WSC  764544
#define WB_WF1  895616
#define WB_WF2  1419904
#define WB_S1   1944192                 /* 2,621,440 each */
#define WB_S2   (WB_S1 + 2621440)
#define WB_S3   (WB_S2 + 2621440)
#define WB_VT   (WB_S3 + 2621440)       /* 512 x 2560 x 2B */
#define WB_H    WB_S2                   /* overlaps S2,S3,VT (dead at FFN time) */

// ============================================================
__global__ void detect_k(const u16* __restrict__ rp, int* __restrict__ flag) {
  int bad = 0;
  for (int i = threadIdx.x; i < 7500; i += 64) {
    float v = bf2f(rp[i]);
    if (!(fabsf(v) < 1e6f)) bad = 1;
  }
  int anybad = __any(bad);
  if (threadIdx.x == 0) flag[0] = anybad ? 1 : 0;   // 1 = f32, 0 = bf16
}

// ============================================================
// prep: weight convert / transpose / zero-fill + uv projection.
//   mode 1: transpose convert   mode 2: zero Vt pad
//   mode 3: vectorized x4 convert   blockIdx.y==6: uv projection
// ============================================================
struct WDesc {
  const void* src[6];
  u16* dst[6];
  int n[6];
  int mode[6];
  int Kd[6], Nd[6];
};
__global__ __launch_bounds__(256) void cvtw_k(WDesc d,
    const void* __restrict__ refp, const void* __restrict__ intr,
    const void* __restrict__ extr, float* __restrict__ uv,
    const int* __restrict__ flag) {
  const int df = flag[0];
  const int i = blockIdx.y;
  if (i == 6) {                          // uv projection task
    for (int idx = blockIdx.x * 256 + threadIdx.x; idx < BB * NCC * LQ; idx += gridDim.x * 256) {
      const int bc = idx / LQ;
      const int q = idx - bc * LQ;
      float R[3][3], tv[3], Kc[3][3], p[3];
#pragma unroll
      for (int a = 0; a < 3; ++a) {
#pragma unroll
        for (int j = 0; j < 3; ++j) {
          R[a][j] = ldf1(extr, bc*16 + a*4 + j, df);
          Kc[a][j] = ldf1(intr, bc*9 + a*3 + j, df);
        }
        tv[a] = ldf1(extr, bc*16 + a*4 + 3, df);
      }
#pragma unroll
      for (int j = 0; j < 3; ++j) p[j] = ldf1(refp, q*3 + j, df) - tv[j];
      float pc[3];
#pragma unroll
      for (int a = 0; a < 3; ++a) pc[a] = R[0][a]*p[0] + R[1][a]*p[1] + R[2][a]*p[2];
      float im[3];
#pragma unroll
      for (int a = 0; a < 3; ++a) im[a] = Kc[a][0]*pc[0] + Kc[a][1]*pc[1] + Kc[a][2]*pc[2];
      const float z = fmaxf(im[2], 1e-5f);
      uv[(size_t)idx*2 + 0] = im[0] / z - 0.5f;
      uv[(size_t)idx*2 + 1] = im[1] / z - 0.5f;
    }
    return;
  }
  const int n = d.n[i];
  for (int j = blockIdx.x * 256 + threadIdx.x; j < n; j += gridDim.x * 256) {
    if (d.mode[i] == 3) {
      if (df) {
        const float4 r = ((const float4*)d.src[i])[j];
        const unsigned int lo = (unsigned int)f2bf(r.x) | ((unsigned int)f2bf(r.y) << 16);
        const unsigned int hi = (unsigned int)f2bf(r.z) | ((unsigned int)f2bf(r.w) << 16);
        ((uint2*)d.dst[i])[j] = make_uint2(lo, hi);
      } else {
        ((uint2*)d.dst[i])[j] = ((const uint2*)d.src[i])[j];
      }
    } else if (d.mode[i] == 2) {
      const int row = j / (LQP - LQ), col = LQ + j % (LQP - LQ);
      d.dst[i][(size_t)row * LQP + col] = 0;
    } else {
      const int K = d.Kd[i], N = d.Nd[i];
      const int nn = j / K, kk = j - nn * K;
      d.dst[i][j] = f2bf(ldf1(d.src[i], (size_t)kk * N + nn, df));
    }
  }
}

// ============================================================
// No-LDS MFMA GEMM, one wave computes 16M x (NT*16)N. (FFN1 only)
// ============================================================
template<int KTPL, int ACT, int NT>
__global__ __launch_bounds__(64) void gemm_nl(
    const u16* __restrict__ Xv, const u16* __restrict__ W,
    const void* __restrict__ bias,
    u16* __restrict__ Y, int M, int N, const int* __restrict__ flag)
{
  const int df = flag[0];
  const int lane = threadIdx.x;
  const int ln15 = lane & 15, l4 = lane >> 4;
  const int m0 = blockIdx.x * 16, n0 = blockIdx.y * (NT * 16);
  const int am = min(m0 + ln15, M - 1);

  f4_t acc[NT];
#pragma unroll
  for (int nt = 0; nt < NT; ++nt) acc[nt] = (f4_t){0.f, 0.f, 0.f, 0.f};

#pragma unroll 8
  for (int k0 = 0; k0 < KTPL; k0 += 32) {
    bf8u a;
    a.q = *(const uint4*)(Xv + (size_t)am * KTPL + k0 + l4 * 8);
#pragma unroll
    for (int nt = 0; nt < NT; ++nt) {
      bf8u b;
      b.q = *(const uint4*)&W[(size_t)(n0 + nt * 16 + ln15) * KTPL + k0 + l4 * 8];
      acc[nt] = __builtin_amdgcn_mfma_f32_16x16x32_bf16(a.v, b.v, acc[nt], 0, 0, 0);
    }
  }
#pragma unroll
  for (int nt = 0; nt < NT; ++nt) {
    const int gn = n0 + nt * 16 + ln15;
    const float bv = ldf1(bias, gn, df);
#pragma unroll
    for (int r = 0; r < 4; ++r) {
      const int gm = m0 + l4 * 4 + r;
      if (gm < M) {
        float x = acc[nt][r] + bv;
        if (ACT) x = 0.5f * x * (1.f + erff(x * 0.70710678118654752f));
        Y[(size_t)gm * N + gn] = f2bf(x);
      }
    }
  }
}

// ============================================================
// GEMM (N=256) + residual + LayerNorm fused.  4 waves: wave wn owns
// cols wn*64 + nt*16 + ln15; all waves share rows m0 + l4*4 + r.
// Two-pass LN: 16-lane shuffle reduce + tiny cross-wave LDS.
// Eliminates the separate ln_k dispatch and the 5MB round-trip.
// ============================================================
template<int KT, int RES, int TOOUT>
__global__ __launch_bounds__(256) void gemm_ln(
    const u16* __restrict__ Xv, const u16* __restrict__ W,
    const void* __restrict__ bias, const void* __restrict__ resv,
    const void* __restrict__ gw, const void* __restrict__ bw,
    void* __restrict__ Yv, int M, const int* __restrict__ flag)
{
  __shared__ float sR[4][16];
  const int df = flag[0];
  const int t = threadIdx.x;
  const int lane = t & 63, wn = t >> 6;
  const int ln15 = lane & 15, l4 = lane >> 4;
  const int m0 = blockIdx.x * 16;
  const int am = min(m0 + ln15, M - 1);

  f4_t acc[4];
#pragma unroll
  for (int nt = 0; nt < 4; ++nt) acc[nt] = (f4_t){0.f, 0.f, 0.f, 0.f};

#pragma unroll 8
  for (int k0 = 0; k0 < KT; k0 += 32) {
    bf8u a;
    a.q = *(const uint4*)(Xv + (size_t)am * KT + k0 + l4 * 8);
#pragma unroll
    for (int nt = 0; nt < 4; ++nt) {
      bf8u b;
      b.q = *(const uint4*)&W[(size_t)(wn * 64 + nt * 16 + ln15) * KT + k0 + l4 * 8];
      acc[nt] = __builtin_amdgcn_mfma_f32_16x16x32_bf16(a.v, b.v, acc[nt], 0, 0, 0);
    }
  }
  // ---- x = acc + bias + residual ----
  float x[4][4];
#pragma unroll
  for (int nt = 0; nt < 4; ++nt) {
    const int gn = wn * 64 + nt * 16 + ln15;
    const float bv = ldf1(bias, gn, df);
#pragma unroll
    for (int r = 0; r < 4; ++r) {
      const int gm = m0 + l4 * 4 + r;
      float xx = acc[nt][r] + bv;
      const size_t ri = (size_t)min(gm, M - 1) * CC + gn;
      if (RES == 1)      xx += bf2f(((const u16*)resv)[ri]);
      else if (RES == 2) xx += ldf1(resv, ri, df);
      x[nt][r] = xx;
    }
  }
  // ---- pass 1: row mean ----
  float ps[4];
#pragma unroll
  for (int r = 0; r < 4; ++r) {
    ps[r] = x[0][r] + x[1][r] + x[2][r] + x[3][r];
#pragma unroll
    for (int o = 1; o < 16; o <<= 1) ps[r] += __shfl_xor(ps[r], o);
  }
  if (ln15 == 0) {
#pragma unroll
    for (int r = 0; r < 4; ++r) sR[wn][l4 * 4 + r] = ps[r];
  }
  __syncthreads();
  float mean[4];
#pragma unroll
  for (int r = 0; r < 4; ++r) {
    const int row = l4 * 4 + r;
    mean[r] = (sR[0][row] + sR[1][row] + sR[2][row] + sR[3][row]) * 0.00390625f;
  }
  __syncthreads();
  // ---- pass 2: row variance ----
  float pq[4];
#pragma unroll
  for (int r = 0; r < 4; ++r) {
    float d0 = x[0][r] - mean[r], d1 = x[1][r] - mean[r];
    float d2 = x[2][r] - mean[r], d3 = x[3][r] - mean[r];
    pq[r] = d0*d0 + d1*d1 + d2*d2 + d3*d3;
#pragma unroll
    for (int o = 1; o < 16; o <<= 1) pq[r] += __shfl_xor(pq[r], o);
  }
  if (ln15 == 0) {
#pragma unroll
    for (int r = 0; r < 4; ++r) sR[wn][l4 * 4 + r] = pq[r];
  }
  __syncthreads();
  float rstd[4];
#pragma unroll
  for (int r = 0; r < 4; ++r) {
    const int row = l4 * 4 + r;
    const float v = (sR[0][row] + sR[1][row] + sR[2][row] + sR[3][row]) * 0.00390625f;
    rstd[r] = rsqrtf(v + 1e-5f);
  }
  // ---- normalize + write ----
#pragma unroll
  for (int nt = 0; nt < 4; ++nt) {
    const int gn = wn * 64 + nt * 16 + ln15;
    const float g = ldf1(gw, gn, df);
    const float be = ldf1(bw, gn, df);
#pragma unroll
    for (int r = 0; r < 4; ++r) {
      const int gm = m0 + l4 * 4 + r;
      if (gm < M) {
        const float y = (x[nt][r] - mean[r]) * rstd[r] * g + be;
        if (TOOUT && df) ((float*)Yv)[(size_t)gm * CC + gn] = y;
        else             ((u16*)Yv)[(size_t)gm * CC + gn] = f2bf(y);
      }
    }
  }
}

// ============================================================
// Fused QKV projection (R5-proven): grid (313, 12), one wave/block.
// ============================================================
__global__ __launch_bounds__(64) void gemm_qkv(
    const void* __restrict__ Xq, const void* __restrict__ Xkv,
    const u16* __restrict__ Wqkv, const void* __restrict__ bias,
    u16* __restrict__ Qo, u16* __restrict__ Ko, u16* __restrict__ Vt,
    const int* __restrict__ flag)
{
  const int df = flag[0];
  const int lane = threadIdx.x;
  const int ln15 = lane & 15, l4 = lane >> 4;
  const int which = blockIdx.y >> 2;
  const int n0 = (blockIdx.y & 3) * 64;
  const void* Xv = (which == 0) ? Xq : Xkv;
  const u16* W = Wqkv + (size_t)which * 65536;
  const int m0 = blockIdx.x * 16;
  const int am = min(m0 + ln15, MROWS - 1);

  f4_t acc[4];
#pragma unroll
  for (int nt = 0; nt < 4; ++nt) acc[nt] = (f4_t){0.f, 0.f, 0.f, 0.f};

#pragma unroll 8
  for (int k0 = 0; k0 < CC; k0 += 32) {
    bf8u a;
    if (df) {
      const float* p = (const float*)Xv + (size_t)am * CC + k0 + l4 * 8;
      float4 r0 = *(const float4*)p, r1 = *(const float4*)(p + 4);
      a.u[0]=f2bf(r0.x); a.u[1]=f2bf(r0.y); a.u[2]=f2bf(r0.z); a.u[3]=f2bf(r0.w);
      a.u[4]=f2bf(r1.x); a.u[5]=f2bf(r1.y); a.u[6]=f2bf(r1.z); a.u[7]=f2bf(r1.w);
    } else {
      a.q = *(const uint4*)((const u16*)Xv + (size_t)am * CC + k0 + l4 * 8);
    }
#pragma unroll
    for (int nt = 0; nt < 4; ++nt) {
      bf8u b;
      b.q = *(const uint4*)&W[(size_t)(n0 + nt * 16 + ln15) * CC + k0 + l4 * 8];
      acc[nt] = __builtin_amdgcn_mfma_f32_16x16x32_bf16(a.v, b.v, acc[nt], 0, 0, 0);
    }
  }
#pragma unroll
  for (int nt = 0; nt < 4; ++nt) {
    const int gn = n0 + nt * 16 + ln15;
    const float bv = ldf1(bias, which * 256 + gn, df);
#pragma unroll
    for (int r = 0; r < 4; ++r) {
      const int gm = m0 + l4 * 4 + r;
      if (gm < MROWS) {
        const float x = acc[nt][r] + bv;
        if (which == 2) {
          const int tt = gm >> 1;
          const int tx = tt & 63;
          const int tp = (tx & 35) | ((tx & 12) << 1) | ((tx & 16) >> 2);
          Vt[(size_t)(gn + (gm & 1) * 256) * LQP + ((tt & ~63) | tp)] = f2bf(x);
        } else {
          u16* Y = (which == 0) ? Qo : Ko;
          Y[(size_t)gm * CC + gn] = f2bf(x);
        }
      }
    }
  }
}

// ============================================================
// Split-K flash attention, swapped-operand + register-resident P.
// This round: shuffle-free defer-max CHECK (16 v_cmp + __any)
// replaces the unconditional fmax-tree + 2 DS shuffles per tile;
// the tree/shuffles/rescale run only when some p > m_r + 8
// (wave-uniform branch; first tile always triggers).
// ============================================================
#define TPW 10
__global__ __launch_bounds__(256) void attn_mf(
    const u16* __restrict__ Qw, const u16* __restrict__ Kw,
    const u16* __restrict__ Vt, u16* __restrict__ Ow)
{
  __shared__ float sO[4][16][33];                // [wave][q][32 d + pad]
  __shared__ float sM[4][16];
  __shared__ float sL[4][16];
  const int t = threadIdx.x;
  const int lane = t & 63, w = t >> 6;
  const int ln15 = lane & 15, l4 = lane >> 4;
  const int q0 = blockIdx.x * 16;
  const int by = blockIdx.y;           // b*8+h
  const int b = by >> 3, h = by & 7;
  const float SCL2E = 0.25505654481f;  // (1/sqrt(32)) * log2(e)

  bf8u aq;
  {
    const int qrow = min(q0 + ln15, LQ - 1);
    bf8u qr; qr.q = *(const uint4*)&Qw[((size_t)qrow * BB + b) * CC + h * 32 + l4 * 8];
#pragma unroll
    for (int i = 0; i < 8; ++i) aq.u[i] = f2bf(bf2f(qr.u[i]) * SCL2E);
  }

  f4_t oacc[2];                        // oacc[dt][r] = O^T[d = dt*16+l4*4+r][q = ln15]
  oacc[0] = (f4_t){0.f,0.f,0.f,0.f};
  oacc[1] = (f4_t){0.f,0.f,0.f,0.f};
  float m_r = -1e30f;
  float l_r = 0.f;                     // per-lane partial (16 of 64 keys/tile)

  const int kt0 = w * TPW;
  const u16* Kbase = &Kw[(size_t)b * CC + h * 32 + l4 * 8];
  const u16* Vbase = &Vt[(size_t)(by * 32 + ln15) * LQP + l4 * 8];

  // ---- prefetch K for first tile ----
  bf8u bkn[4];
#pragma unroll
  for (int nt = 0; nt < 4; ++nt)
    bkn[nt].q = *(const uint4*)&Kbase[(size_t)(kt0 * 64 + nt * 16 + ln15) * CC];

  for (int kt = kt0; kt < kt0 + TPW; ++kt) {
    const int kb = kt * 64;
    // ---- Vt loads (consumed last): latency hides under QK+softmax ----
    bf8u av[2][2];
#pragma unroll
    for (int m = 0; m < 2; ++m)
#pragma unroll
      for (int dt = 0; dt < 2; ++dt)
        av[m][dt].q = *(const uint4*)&Vbase[(size_t)(dt * 16) * LQP + kb + m * 32];
    // ---- consume prefetched K; issue next tile's K loads ----
    bf8u bk[4];
#pragma unroll
    for (int nt = 0; nt < 4; ++nt) bk[nt] = bkn[nt];
    if (kt + 1 < kt0 + TPW) {
#pragma unroll
      for (int nt = 0; nt < 4; ++nt)
        bkn[nt].q = *(const uint4*)&Kbase[(size_t)(kb + 64 + nt * 16 + ln15) * CC];
    }
    f4_t sv[4];
    __builtin_amdgcn_s_setprio(1);
#pragma unroll
    for (int nt = 0; nt < 4; ++nt) {
      f4_t z = (f4_t){0.f,0.f,0.f,0.f};
      sv[nt] = __builtin_amdgcn_mfma_f32_16x16x32_bf16(bk[nt].v, aq.v, z, 0, 0, 0);
    }
    __builtin_amdgcn_s_setprio(0);
    float p[4][4];
    if (kb + 64 <= LQ) {
#pragma unroll
      for (int nt = 0; nt < 4; ++nt)
#pragma unroll
        for (int r = 0; r < 4; ++r) p[nt][r] = sv[nt][r];
    } else {
#pragma unroll
      for (int nt = 0; nt < 4; ++nt)
#pragma unroll
        for (int r = 0; r < 4; ++r)
          p[nt][r] = (kb + nt * 16 + l4 * 4 + r < LQ) ? sv[nt][r] : -1e30f;
    }
    // ---- shuffle-free defer-max check ----
    const float thr = m_r + 8.f;
    bool nd = false;
#pragma unroll
    for (int nt = 0; nt < 4; ++nt)
#pragma unroll
      for (int r = 0; r < 4; ++r) nd |= (p[nt][r] > thr);
    if (__any(nd)) {
      const float m0 = fmaxf(fmaxf(p[0][0], p[0][1]), fmaxf(p[0][2], p[0][3]));
      const float m1 = fmaxf(fmaxf(p[1][0], p[1][1]), fmaxf(p[1][2], p[1][3]));
      const float m2 = fmaxf(fmaxf(p[2][0], p[2][1]), fmaxf(p[2][2], p[2][3]));
      const float m3 = fmaxf(fmaxf(p[3][0], p[3][1]), fmaxf(p[3][2], p[3][3]));
      float mloc = fmaxf(fmaxf(m0, m1), fmaxf(m2, m3));
      mloc = fmaxf(mloc, __shfl_xor(mloc, 16));
      mloc = fmaxf(mloc, __shfl_xor(mloc, 32));
      const float mn = fmaxf(m_r, mloc);      // per-lane, q-consistent
      const float alpha = __builtin_amdgcn_exp2f(m_r - mn);
      m_r = mn;
      l_r *= alpha;
#pragma unroll
      for (int r = 0; r < 4; ++r) { oacc[0][r] *= alpha; oacc[1][r] *= alpha; }
    }
    float s = 0.f;
#pragma unroll
    for (int nt = 0; nt < 4; ++nt) {
#pragma unroll
      for (int r = 0; r < 4; ++r) {
        const float e = __builtin_amdgcn_exp2f(p[nt][r] - m_r);
        p[nt][r] = e; s += e;
      }
    }
    l_r += s;
    // ---- PV with register-resident P (permuted virtual k-slots) ----
    __builtin_amdgcn_s_setprio(1);
#pragma unroll
    for (int m = 0; m < 2; ++m) {
      bf8u pb;                        // slot i -> key (2m+(i>>2))*16 + l4*4 + (i&3)
#pragma unroll
      for (int i = 0; i < 8; ++i) pb.u[i] = f2bf(p[2 * m + (i >> 2)][i & 3]);
#pragma unroll
      for (int dt = 0; dt < 2; ++dt)
        oacc[dt] = __builtin_amdgcn_mfma_f32_16x16x32_bf16(av[m][dt].v, pb.v, oacc[dt], 0, 0, 0);
    }
    __builtin_amdgcn_s_setprio(0);
  }
  // ---- reduce l across the 4 l4-lanes of each q (consistent scaling) ----
  l_r += __shfl_xor(l_r, 16);
  l_r += __shfl_xor(l_r, 32);
  // ---- write partials, merge in LDS ----
#pragma unroll
  for (int dt = 0; dt < 2; ++dt)
#pragma unroll
    for (int r = 0; r < 4; ++r)
      sO[w][ln15][dt * 16 + l4 * 4 + r] = oacc[dt][r];
  if (l4 == 0) { sM[w][ln15] = m_r; sL[w][ln15] = l_r; }
  __syncthreads();
#pragma unroll
  for (int i = t; i < 512; i += 256) {
    const int row = i >> 5, col = i & 31;
    const float M = fmaxf(fmaxf(sM[0][row], sM[1][row]), fmaxf(sM[2][row], sM[3][row]));
    float l = 0.f, O = 0.f;
#pragma unroll
    for (int w4 = 0; w4 < 4; ++w4) {
      const float sc = __builtin_amdgcn_exp2f(sM[w4][row] - M);
      l += sc * sL[w4][row];
      O += sc * sO[w4][row][col];
    }
    const int q = q0 + row;
    if (q < LQ)
      Ow[((size_t)q * BB + b) * CC + h * 32 + col] = f2bf(O / l);
  }
}

// ============================================================
// Grid-sample (R0-R4 proven version).
// ============================================================
__global__ __launch_bounds__(256) void samp_k(
    const void* __restrict__ feat, const float* __restrict__ uv,
    u16* __restrict__ S, const int* __restrict__ flag)
{
  const int df = flag[0];
  const int c = blockIdx.x;
  const int b = blockIdx.y / 5;
  const int ch = blockIdx.y % 5;
  const int qend = min((ch + 1) * 500, LQ);
  for (int q = ch * 500 + threadIdx.x; q < qend; q += 256) {
    float acc = 0.f;
#pragma unroll
    for (int cam = 0; cam < NCC; ++cam) {
      const int bc = b * NCC + cam;
      const float x = uv[((size_t)bc * LQ + q) * 2 + 0];
      const float y = uv[((size_t)bc * LQ + q) * 2 + 1];
      const float xf = floorf(x), yf = floorf(y);
      const int x0 = (int)xf, y0 = (int)yf;
      const float wx = x - xf, wy = y - yf;
      const size_t base = ((size_t)bc * CC + c) * (HFF * WFF);
      const bool vx0 = (x0 >= 0) & (x0 < WFF);
      const bool vx1 = (x0 + 1 >= 0) & (x0 + 1 < WFF);
      const bool vy0 = (y0 >= 0) & (y0 < HFF);
      const bool vy1 = (y0 + 1 >= 0) & (y0 + 1 < HFF);
      if (vy0) {
        const size_t rb = base + (size_t)y0 * WFF;
        if (vx0) acc += (1.f - wx) * (1.f - wy) * ldf1(feat, rb + x0, df);
        if (vx1) acc += wx * (1.f - wy) * ldf1(feat, rb + x0 + 1, df);
      }
      if (vy1) {
        const size_t rb = base + (size_t)(y0 + 1) * WFF;
        if (vx0) acc += (1.f - wx) * wy * ldf1(feat, rb + x0, df);
        if (vx1) acc += wx * wy * ldf1(feat, rb + x0 + 1, df);
      }
    }
    S[((size_t)q * BB + b) * CC + c] = f2bf(acc * (1.f / 6.f));
  }
}

// ============================================================
extern "C" void kernel_launch(void* const* d_in, const int* in_sizes, int n_in,
                              void* d_out, int out_size, void* d_ws, size_t ws_size,
                              hipStream_t stream) {
  (void)in_sizes; (void)n_in; (void)out_size; (void)ws_size;
  char* base = (char*)d_ws;
  int* flag = (int*)base;
  float* UV = (float*)(base + WB_UV);
  u16* WQKV = (u16*)(base + WB_WQKV);
  u16* WOP  = (u16*)(base + WB_WOP);
  u16* WSC  = (u16*)(base + WB_WSC);
  u16* WF1  = (u16*)(base + WB_WF1);
  u16* WF2  = (u16*)(base + WB_WF2);
  u16* S1 = (u16*)(base + WB_S1);
  u16* S2 = (u16*)(base + WB_S2);
  u16* S3 = (u16*)(base + WB_S3);
  u16* VT = (u16*)(base + WB_VT);
  u16* H  = (u16*)(base + WB_H);

  detect_k<<<1, 64, 0, stream>>>((const u16*)d_in[3], flag);

  WDesc wd;
  wd.src[0] = d_in[7];  wd.dst[0] = WQKV; wd.n[0] = 49152;  wd.mode[0] = 3; wd.Kd[0] = 0;    wd.Nd[0] = 0;
  wd.src[1] = d_in[9];  wd.dst[1] = WOP;  wd.n[1] = 16384;  wd.mode[1] = 3; wd.Kd[1] = 0;    wd.Nd[1] = 0;
  wd.src[2] = d_in[13]; wd.dst[2] = WSC;  wd.n[2] = 16384;  wd.mode[2] = 3; wd.Kd[2] = 0;    wd.Nd[2] = 0;
  wd.src[3] = d_in[17]; wd.dst[3] = WF1;  wd.n[3] = 262144; wd.mode[3] = 1; wd.Kd[3] = 256;  wd.Nd[3] = 1024;
  wd.src[4] = d_in[19]; wd.dst[4] = WF2;  wd.n[4] = 262144; wd.mode[4] = 1; wd.Kd[4] = 1024; wd.Nd[4] = 256;
  wd.src[5] = nullptr;  wd.dst[5] = VT;   wd.n[5] = 512 * (LQP - LQ); wd.mode[5] = 2; wd.Kd[5] = 0; wd.Nd[5] = 0;
  cvtw_k<<<dim3(128, 7), 256, 0, stream>>>(wd, d_in[3], d_in[4], d_in[5], UV, flag);

  // Fused QKV projections: Q->S1, K->S2, V->VT (transposed + permuted store)
  gemm_qkv<<<dim3(313, 12), 64, 0, stream>>>(d_in[0], d_in[1], WQKV, d_in[8], S1, S2, VT, flag);

  attn_mf<<<dim3(157, 16), 256, 0, stream>>>(S1, S2, VT, S3);

  // out-proj (+bevq residual) + LN1 -> S2
  gemm_ln<256,2,0><<<313, 256, 0, stream>>>(S3, WOP, d_in[10], d_in[0], d_in[11], d_in[12], S2, MROWS, flag);

  // sampling -> VT slot (dead after attn)
  samp_k<<<dim3(CC, BB * 5), 256, 0, stream>>>(d_in[2], UV, VT, flag);

  // SCA (+S2 residual) + LN2 -> S1
  gemm_ln<256,1,0><<<313, 256, 0, stream>>>(VT, WSC, d_in[14], S2, d_in[15], d_in[16], S1, MROWS, flag);

  // FFN: gelu(S1 @ W1 + b1) -> H ; (H @ W2 + b2 + S1) + LN3 -> out
  gemm_nl<256,1,4><<<dim3(313, 16), 64, 0, stream>>>(S1, WF1, d_in[18], H, MROWS, DFF, flag);
  gemm_ln<1024,1,1><<<313, 256, 0, stream>>>(H, WF2, d_in[20], S1, d_in[21], d_in[22], d_out, MROWS, flag);
}

// Round 8
// 464.037 us; speedup vs baseline: 1.1871x; 1.0854x over previous
//
#include <hip/hip_runtime.h>

typedef unsigned short u16;
typedef __attribute__((ext_vector_type(8))) __bf16 bf8_t;
typedef __attribute__((ext_vector_type(4))) float f4_t;

union bf8u { u16 u[8]; bf8_t v; uint4 q; };

// ---------- bf16 helpers ----------
__device__ __forceinline__ float bf2f(u16 v) {
  return __uint_as_float(((unsigned int)v) << 16);
}
__device__ __forceinline__ u16 f2bf(float f) {
  union { __bf16 h; u16 u; } c;          // gfx950: single v_cvt_pk_bf16_f32 (RNE)
  c.h = (__bf16)f;
  return c.u;
}
__device__ __forceinline__ float bflo(unsigned int w) { return __uint_as_float(w << 16); }
__device__ __forceinline__ float bfhi(unsigned int w) { return __uint_as_float(w & 0xFFFF0000u); }
__device__ __forceinline__ float ldf1(const void* p, size_t i, int isf32) {
  return isf32 ? ((const float*)p)[i] : bf2f(((const u16*)p)[i]);
}
// packed f32x2 -> bf16x2 (RNE), single HW instr
__device__ __forceinline__ unsigned int cvtpk(float lo, float hi) {
  unsigned int w;
  asm("v_cvt_pk_bf16_f32 %0, %1, %2" : "=v"(w) : "v"(lo), "v"(hi));
  return w;
}

// ---------- sizes ----------
#define LQ    2500
#define LQP   2560      /* padded token count for Vt */
#define BB    2
#define CC    256
#define NCC   6
#define HFF   64
#define WFF   176
#define DFF   1024
#define MROWS 5000

// ---------- workspace byte offsets (end < 20.7MB proven-safe) ----------
#define WB_UV   256
#define WB_WQKV 240256
#define WB_WOP  633472
#define WB_WSC  764544
#define WB_WF1  895616
#define WB_WF2  1419904
#define WB_S1   1944192                 /* 2,621,440 each */
#define WB_S2   (WB_S1 + 2621440)
#define WB_S3   (WB_S2 + 2621440)
#define WB_VT   (WB_S3 + 2621440)       /* 512 x 2560 x 2B */
#define WB_H    WB_S2                   /* overlaps S2,S3,VT (dead at FFN time) */

// ============================================================
__global__ void detect_k(const u16* __restrict__ rp, int* __restrict__ flag) {
  int bad = 0;
  for (int i = threadIdx.x; i < 7500; i += 64) {
    float v = bf2f(rp[i]);
    if (!(fabsf(v) < 1e6f)) bad = 1;
  }
  int anybad = __any(bad);
  if (threadIdx.x == 0) flag[0] = anybad ? 1 : 0;   // 1 = f32, 0 = bf16
}

// ============================================================
// prep: weight convert / transpose / zero-fill + uv projection.
//   mode 1: transpose convert   mode 2: zero Vt pad
//   mode 3: vectorized x4 convert   blockIdx.y==6: uv projection
// ============================================================
struct WDesc {
  const void* src[6];
  u16* dst[6];
  int n[6];
  int mode[6];
  int Kd[6], Nd[6];
};
__global__ __launch_bounds__(256) void cvtw_k(WDesc d,
    const void* __restrict__ refp, const void* __restrict__ intr,
    const void* __restrict__ extr, float* __restrict__ uv,
    const int* __restrict__ flag) {
  const int df = flag[0];
  const int i = blockIdx.y;
  if (i == 6) {                          // uv projection task
    for (int idx = blockIdx.x * 256 + threadIdx.x; idx < BB * NCC * LQ; idx += gridDim.x * 256) {
      const int bc = idx / LQ;
      const int q = idx - bc * LQ;
      float R[3][3], tv[3], Kc[3][3], p[3];
#pragma unroll
      for (int a = 0; a < 3; ++a) {
#pragma unroll
        for (int j = 0; j < 3; ++j) {
          R[a][j] = ldf1(extr, bc*16 + a*4 + j, df);
          Kc[a][j] = ldf1(intr, bc*9 + a*3 + j, df);
        }
        tv[a] = ldf1(extr, bc*16 + a*4 + 3, df);
      }
#pragma unroll
      for (int j = 0; j < 3; ++j) p[j] = ldf1(refp, q*3 + j, df) - tv[j];
      float pc[3];
#pragma unroll
      for (int a = 0; a < 3; ++a) pc[a] = R[0][a]*p[0] + R[1][a]*p[1] + R[2][a]*p[2];
      float im[3];
#pragma unroll
      for (int a = 0; a < 3; ++a) im[a] = Kc[a][0]*pc[0] + Kc[a][1]*pc[1] + Kc[a][2]*pc[2];
      const float z = fmaxf(im[2], 1e-5f);
      uv[(size_t)idx*2 + 0] = im[0] / z - 0.5f;
      uv[(size_t)idx*2 + 1] = im[1] / z - 0.5f;
    }
    return;
  }
  const int n = d.n[i];
  for (int j = blockIdx.x * 256 + threadIdx.x; j < n; j += gridDim.x * 256) {
    if (d.mode[i] == 3) {
      if (df) {
        const float4 r = ((const float4*)d.src[i])[j];
        const unsigned int lo = (unsigned int)f2bf(r.x) | ((unsigned int)f2bf(r.y) << 16);
        const unsigned int hi = (unsigned int)f2bf(r.z) | ((unsigned int)f2bf(r.w) << 16);
        ((uint2*)d.dst[i])[j] = make_uint2(lo, hi);
      } else {
        ((uint2*)d.dst[i])[j] = ((const uint2*)d.src[i])[j];
      }
    } else if (d.mode[i] == 2) {
      const int row = j / (LQP - LQ), col = LQ + j % (LQP - LQ);
      d.dst[i][(size_t)row * LQP + col] = 0;
    } else {
      const int K = d.Kd[i], N = d.Nd[i];
      const int nn = j / K, kk = j - nn * K;
      d.dst[i][j] = f2bf(ldf1(d.src[i], (size_t)kk * N + nn, df));
    }
  }
}

// ============================================================
// No-LDS MFMA GEMM, one wave computes 16M x (NT*16)N. (FFN1 only)
// ============================================================
template<int KTPL, int ACT, int NT>
__global__ __launch_bounds__(64) void gemm_nl(
    const u16* __restrict__ Xv, const u16* __restrict__ W,
    const void* __restrict__ bias,
    u16* __restrict__ Y, int M, int N, const int* __restrict__ flag)
{
  const int df = flag[0];
  const int lane = threadIdx.x;
  const int ln15 = lane & 15, l4 = lane >> 4;
  const int m0 = blockIdx.x * 16, n0 = blockIdx.y * (NT * 16);
  const int am = min(m0 + ln15, M - 1);

  f4_t acc[NT];
#pragma unroll
  for (int nt = 0; nt < NT; ++nt) acc[nt] = (f4_t){0.f, 0.f, 0.f, 0.f};

#pragma unroll 8
  for (int k0 = 0; k0 < KTPL; k0 += 32) {
    bf8u a;
    a.q = *(const uint4*)(Xv + (size_t)am * KTPL + k0 + l4 * 8);
#pragma unroll
    for (int nt = 0; nt < NT; ++nt) {
      bf8u b;
      b.q = *(const uint4*)&W[(size_t)(n0 + nt * 16 + ln15) * KTPL + k0 + l4 * 8];
      acc[nt] = __builtin_amdgcn_mfma_f32_16x16x32_bf16(a.v, b.v, acc[nt], 0, 0, 0);
    }
  }
#pragma unroll
  for (int nt = 0; nt < NT; ++nt) {
    const int gn = n0 + nt * 16 + ln15;
    const float bv = ldf1(bias, gn, df);
#pragma unroll
    for (int r = 0; r < 4; ++r) {
      const int gm = m0 + l4 * 4 + r;
      if (gm < M) {
        float x = acc[nt][r] + bv;
        if (ACT) x = 0.5f * x * (1.f + erff(x * 0.70710678118654752f));
        Y[(size_t)gm * N + gn] = f2bf(x);
      }
    }
  }
}

// ============================================================
// GEMM (N=256) + residual + LayerNorm fused.  4 waves: wave wn owns
// cols wn*64 + nt*16 + ln15; all waves share rows m0 + l4*4 + r.
// Two-pass LN: 16-lane shuffle reduce + tiny cross-wave LDS.
// ============================================================
template<int KT, int RES, int TOOUT>
__global__ __launch_bounds__(256) void gemm_ln(
    const u16* __restrict__ Xv, const u16* __restrict__ W,
    const void* __restrict__ bias, const void* __restrict__ resv,
    const void* __restrict__ gw, const void* __restrict__ bw,
    void* __restrict__ Yv, int M, const int* __restrict__ flag)
{
  __shared__ float sR[4][16];
  const int df = flag[0];
  const int t = threadIdx.x;
  const int lane = t & 63, wn = t >> 6;
  const int ln15 = lane & 15, l4 = lane >> 4;
  const int m0 = blockIdx.x * 16;
  const int am = min(m0 + ln15, M - 1);

  f4_t acc[4];
#pragma unroll
  for (int nt = 0; nt < 4; ++nt) acc[nt] = (f4_t){0.f, 0.f, 0.f, 0.f};

#pragma unroll 8
  for (int k0 = 0; k0 < KT; k0 += 32) {
    bf8u a;
    a.q = *(const uint4*)(Xv + (size_t)am * KT + k0 + l4 * 8);
#pragma unroll
    for (int nt = 0; nt < 4; ++nt) {
      bf8u b;
      b.q = *(const uint4*)&W[(size_t)(wn * 64 + nt * 16 + ln15) * KT + k0 + l4 * 8];
      acc[nt] = __builtin_amdgcn_mfma_f32_16x16x32_bf16(a.v, b.v, acc[nt], 0, 0, 0);
    }
  }
  // ---- x = acc + bias + residual ----
  float x[4][4];
#pragma unroll
  for (int nt = 0; nt < 4; ++nt) {
    const int gn = wn * 64 + nt * 16 + ln15;
    const float bv = ldf1(bias, gn, df);
#pragma unroll
    for (int r = 0; r < 4; ++r) {
      const int gm = m0 + l4 * 4 + r;
      float xx = acc[nt][r] + bv;
      const size_t ri = (size_t)min(gm, M - 1) * CC + gn;
      if (RES == 1)      xx += bf2f(((const u16*)resv)[ri]);
      else if (RES == 2) xx += ldf1(resv, ri, df);
      x[nt][r] = xx;
    }
  }
  // ---- pass 1: row mean ----
  float ps[4];
#pragma unroll
  for (int r = 0; r < 4; ++r) {
    ps[r] = x[0][r] + x[1][r] + x[2][r] + x[3][r];
#pragma unroll
    for (int o = 1; o < 16; o <<= 1) ps[r] += __shfl_xor(ps[r], o);
  }
  if (ln15 == 0) {
#pragma unroll
    for (int r = 0; r < 4; ++r) sR[wn][l4 * 4 + r] = ps[r];
  }
  __syncthreads();
  float mean[4];
#pragma unroll
  for (int r = 0; r < 4; ++r) {
    const int row = l4 * 4 + r;
    mean[r] = (sR[0][row] + sR[1][row] + sR[2][row] + sR[3][row]) * 0.00390625f;
  }
  __syncthreads();
  // ---- pass 2: row variance ----
  float pq[4];
#pragma unroll
  for (int r = 0; r < 4; ++r) {
    float d0 = x[0][r] - mean[r], d1 = x[1][r] - mean[r];
    float d2 = x[2][r] - mean[r], d3 = x[3][r] - mean[r];
    pq[r] = d0*d0 + d1*d1 + d2*d2 + d3*d3;
#pragma unroll
    for (int o = 1; o < 16; o <<= 1) pq[r] += __shfl_xor(pq[r], o);
  }
  if (ln15 == 0) {
#pragma unroll
    for (int r = 0; r < 4; ++r) sR[wn][l4 * 4 + r] = pq[r];
  }
  __syncthreads();
  float rstd[4];
#pragma unroll
  for (int r = 0; r < 4; ++r) {
    const int row = l4 * 4 + r;
    const float v = (sR[0][row] + sR[1][row] + sR[2][row] + sR[3][row]) * 0.00390625f;
    rstd[r] = rsqrtf(v + 1e-5f);
  }
  // ---- normalize + write ----
#pragma unroll
  for (int nt = 0; nt < 4; ++nt) {
    const int gn = wn * 64 + nt * 16 + ln15;
    const float g = ldf1(gw, gn, df);
    const float be = ldf1(bw, gn, df);
#pragma unroll
    for (int r = 0; r < 4; ++r) {
      const int gm = m0 + l4 * 4 + r;
      if (gm < M) {
        const float y = (x[nt][r] - mean[r]) * rstd[r] * g + be;
        if (TOOUT && df) ((float*)Yv)[(size_t)gm * CC + gn] = y;
        else             ((u16*)Yv)[(size_t)gm * CC + gn] = f2bf(y);
      }
    }
  }
}

// ============================================================
// Fused QKV projection (R5-proven): grid (313, 12), one wave/block.
// ============================================================
__global__ __launch_bounds__(64) void gemm_qkv(
    const void* __restrict__ Xq, const void* __restrict__ Xkv,
    const u16* __restrict__ Wqkv, const void* __restrict__ bias,
    u16* __restrict__ Qo, u16* __restrict__ Ko, u16* __restrict__ Vt,
    const int* __restrict__ flag)
{
  const int df = flag[0];
  const int lane = threadIdx.x;
  const int ln15 = lane & 15, l4 = lane >> 4;
  const int which = blockIdx.y >> 2;
  const int n0 = (blockIdx.y & 3) * 64;
  const void* Xv = (which == 0) ? Xq : Xkv;
  const u16* W = Wqkv + (size_t)which * 65536;
  const int m0 = blockIdx.x * 16;
  const int am = min(m0 + ln15, MROWS - 1);

  f4_t acc[4];
#pragma unroll
  for (int nt = 0; nt < 4; ++nt) acc[nt] = (f4_t){0.f, 0.f, 0.f, 0.f};

#pragma unroll 8
  for (int k0 = 0; k0 < CC; k0 += 32) {
    bf8u a;
    if (df) {
      const float* p = (const float*)Xv + (size_t)am * CC + k0 + l4 * 8;
      float4 r0 = *(const float4*)p, r1 = *(const float4*)(p + 4);
      a.u[0]=f2bf(r0.x); a.u[1]=f2bf(r0.y); a.u[2]=f2bf(r0.z); a.u[3]=f2bf(r0.w);
      a.u[4]=f2bf(r1.x); a.u[5]=f2bf(r1.y); a.u[6]=f2bf(r1.z); a.u[7]=f2bf(r1.w);
    } else {
      a.q = *(const uint4*)((const u16*)Xv + (size_t)am * CC + k0 + l4 * 8);
    }
#pragma unroll
    for (int nt = 0; nt < 4; ++nt) {
      bf8u b;
      b.q = *(const uint4*)&W[(size_t)(n0 + nt * 16 + ln15) * CC + k0 + l4 * 8];
      acc[nt] = __builtin_amdgcn_mfma_f32_16x16x32_bf16(a.v, b.v, acc[nt], 0, 0, 0);
    }
  }
#pragma unroll
  for (int nt = 0; nt < 4; ++nt) {
    const int gn = n0 + nt * 16 + ln15;
    const float bv = ldf1(bias, which * 256 + gn, df);
#pragma unroll
    for (int r = 0; r < 4; ++r) {
      const int gm = m0 + l4 * 4 + r;
      if (gm < MROWS) {
        const float x = acc[nt][r] + bv;
        if (which == 2) {
          const int tt = gm >> 1;
          const int tx = tt & 63;
          const int tp = (tx & 35) | ((tx & 12) << 1) | ((tx & 16) >> 2);
          Vt[(size_t)(gn + (gm & 1) * 256) * LQP + ((tt & ~63) | tp)] = f2bf(x);
        } else {
          u16* Y = (which == 0) ? Qo : Ko;
          Y[(size_t)gm * CC + gn] = f2bf(x);
        }
      }
    }
  }
}

// ============================================================
// Split-K flash attention, swapped-operand + register-resident P.
// This round: 32 q per wave (two 16-q groups A/B sharing the SAME
// K-tile and V-tile loads) — halves total load/miss count (the
// measured stall budget) at constant aggregate VALU.  P->bf16 via
// v_cvt_pk_bf16_f32 (8 pk-cvts per group).  Defer-max unchanged.
// ============================================================
#define TPW 10
__global__ __launch_bounds__(256) void attn_mf(
    const u16* __restrict__ Qw, const u16* __restrict__ Kw,
    const u16* __restrict__ Vt, u16* __restrict__ Ow)
{
  __shared__ float sO[4][32][33];                // [wave][q][32 d + pad]
  __shared__ float sM[4][32];
  __shared__ float sL[4][32];
  const int t = threadIdx.x;
  const int lane = t & 63, w = t >> 6;
  const int ln15 = lane & 15, l4 = lane >> 4;
  const int q0 = blockIdx.x * 32;
  const int by = blockIdx.y;           // b*8+h
  const int b = by >> 3, h = by & 7;
  const float SCL2E = 0.25505654481f;  // (1/sqrt(32)) * log2(e)

  bf8u aqA, aqB;
  {
    const int qra = min(q0 + ln15, LQ - 1);
    const int qrb = min(q0 + 16 + ln15, LQ - 1);
    bf8u qr;
    qr.q = *(const uint4*)&Qw[((size_t)qra * BB + b) * CC + h * 32 + l4 * 8];
#pragma unroll
    for (int i = 0; i < 8; ++i) aqA.u[i] = f2bf(bf2f(qr.u[i]) * SCL2E);
    qr.q = *(const uint4*)&Qw[((size_t)qrb * BB + b) * CC + h * 32 + l4 * 8];
#pragma unroll
    for (int i = 0; i < 8; ++i) aqB.u[i] = f2bf(bf2f(qr.u[i]) * SCL2E);
  }

  f4_t oaccA[2], oaccB[2];
  oaccA[0] = (f4_t){0.f,0.f,0.f,0.f}; oaccA[1] = (f4_t){0.f,0.f,0.f,0.f};
  oaccB[0] = (f4_t){0.f,0.f,0.f,0.f}; oaccB[1] = (f4_t){0.f,0.f,0.f,0.f};
  float mA = -1e30f, lA = 0.f;
  float mB = -1e30f, lB = 0.f;

  const int kt0 = w * TPW;
  const u16* Kbase = &Kw[(size_t)b * CC + h * 32 + l4 * 8];
  const u16* Vbase = &Vt[(size_t)(by * 32 + ln15) * LQP + l4 * 8];

  // ---- prefetch K for first tile ----
  bf8u bkn[4];
#pragma unroll
  for (int nt = 0; nt < 4; ++nt)
    bkn[nt].q = *(const uint4*)&Kbase[(size_t)(kt0 * 64 + nt * 16 + ln15) * CC];

  for (int kt = kt0; kt < kt0 + TPW; ++kt) {
    const int kb = kt * 64;
    // ---- Vt loads (consumed last): latency hides under QK+softmax ----
    bf8u av[2][2];
#pragma unroll
    for (int m = 0; m < 2; ++m)
#pragma unroll
      for (int dt = 0; dt < 2; ++dt)
        av[m][dt].q = *(const uint4*)&Vbase[(size_t)(dt * 16) * LQP + kb + m * 32];
    // ---- QK for both q-groups from the shared K fragments ----
    f4_t svA[4], svB[4];
    __builtin_amdgcn_s_setprio(1);
#pragma unroll
    for (int nt = 0; nt < 4; ++nt) {
      f4_t z = (f4_t){0.f,0.f,0.f,0.f};
      svA[nt] = __builtin_amdgcn_mfma_f32_16x16x32_bf16(bkn[nt].v, aqA.v, z, 0, 0, 0);
      f4_t z2 = (f4_t){0.f,0.f,0.f,0.f};
      svB[nt] = __builtin_amdgcn_mfma_f32_16x16x32_bf16(bkn[nt].v, aqB.v, z2, 0, 0, 0);
    }
    __builtin_amdgcn_s_setprio(0);
    // ---- issue next tile's K loads ----
    if (kt + 1 < kt0 + TPW) {
#pragma unroll
      for (int nt = 0; nt < 4; ++nt)
        bkn[nt].q = *(const uint4*)&Kbase[(size_t)(kb + 64 + nt * 16 + ln15) * CC];
    }
    float pA[4][4], pB[4][4];
    if (kb + 64 <= LQ) {
#pragma unroll
      for (int nt = 0; nt < 4; ++nt)
#pragma unroll
        for (int r = 0; r < 4; ++r) { pA[nt][r] = svA[nt][r]; pB[nt][r] = svB[nt][r]; }
    } else {
#pragma unroll
      for (int nt = 0; nt < 4; ++nt)
#pragma unroll
        for (int r = 0; r < 4; ++r) {
          const bool ok = (kb + nt * 16 + l4 * 4 + r < LQ);
          pA[nt][r] = ok ? svA[nt][r] : -1e30f;
          pB[nt][r] = ok ? svB[nt][r] : -1e30f;
        }
    }
    // ---- group A softmax ----
    {
      const float thr = mA + 8.f;
      bool nd = false;
#pragma unroll
      for (int nt = 0; nt < 4; ++nt)
#pragma unroll
        for (int r = 0; r < 4; ++r) nd |= (pA[nt][r] > thr);
      if (__any(nd)) {
        const float x0 = fmaxf(fmaxf(pA[0][0], pA[0][1]), fmaxf(pA[0][2], pA[0][3]));
        const float x1 = fmaxf(fmaxf(pA[1][0], pA[1][1]), fmaxf(pA[1][2], pA[1][3]));
        const float x2 = fmaxf(fmaxf(pA[2][0], pA[2][1]), fmaxf(pA[2][2], pA[2][3]));
        const float x3 = fmaxf(fmaxf(pA[3][0], pA[3][1]), fmaxf(pA[3][2], pA[3][3]));
        float mloc = fmaxf(fmaxf(x0, x1), fmaxf(x2, x3));
        mloc = fmaxf(mloc, __shfl_xor(mloc, 16));
        mloc = fmaxf(mloc, __shfl_xor(mloc, 32));
        const float mn = fmaxf(mA, mloc);
        const float alpha = __builtin_amdgcn_exp2f(mA - mn);
        mA = mn;
        lA *= alpha;
#pragma unroll
        for (int r = 0; r < 4; ++r) { oaccA[0][r] *= alpha; oaccA[1][r] *= alpha; }
      }
      float s = 0.f;
#pragma unroll
      for (int nt = 0; nt < 4; ++nt)
#pragma unroll
        for (int r = 0; r < 4; ++r) {
          const float e = __builtin_amdgcn_exp2f(pA[nt][r] - mA);
          pA[nt][r] = e; s += e;
        }
      lA += s;
    }
    // ---- group B softmax ----
    {
      const float thr = mB + 8.f;
      bool nd = false;
#pragma unroll
      for (int nt = 0; nt < 4; ++nt)
#pragma unroll
        for (int r = 0; r < 4; ++r) nd |= (pB[nt][r] > thr);
      if (__any(nd)) {
        const float x0 = fmaxf(fmaxf(pB[0][0], pB[0][1]), fmaxf(pB[0][2], pB[0][3]));
        const float x1 = fmaxf(fmaxf(pB[1][0], pB[1][1]), fmaxf(pB[1][2], pB[1][3]));
        const float x2 = fmaxf(fmaxf(pB[2][0], pB[2][1]), fmaxf(pB[2][2], pB[2][3]));
        const float x3 = fmaxf(fmaxf(pB[3][0], pB[3][1]), fmaxf(pB[3][2], pB[3][3]));
        float mloc = fmaxf(fmaxf(x0, x1), fmaxf(x2, x3));
        mloc = fmaxf(mloc, __shfl_xor(mloc, 16));
        mloc = fmaxf(mloc, __shfl_xor(mloc, 32));
        const float mn = fmaxf(mB, mloc);
        const float alpha = __builtin_amdgcn_exp2f(mB - mn);
        mB = mn;
        lB *= alpha;
#pragma unroll
        for (int r = 0; r < 4; ++r) { oaccB[0][r] *= alpha; oaccB[1][r] *= alpha; }
      }
      float s = 0.f;
#pragma unroll
      for (int nt = 0; nt < 4; ++nt)
#pragma unroll
        for (int r = 0; r < 4; ++r) {
          const float e = __builtin_amdgcn_exp2f(pB[nt][r] - mB);
          pB[nt][r] = e; s += e;
        }
      lB += s;
    }
    // ---- PV: both groups share av fragments ----
    __builtin_amdgcn_s_setprio(1);
#pragma unroll
    for (int m = 0; m < 2; ++m) {
      bf8u pba, pbb;                   // slot i -> key (2m+(i>>2))*16 + l4*4 + (i&3)
      pba.q = make_uint4(cvtpk(pA[2*m][0], pA[2*m][1]),   cvtpk(pA[2*m][2], pA[2*m][3]),
                         cvtpk(pA[2*m+1][0], pA[2*m+1][1]), cvtpk(pA[2*m+1][2], pA[2*m+1][3]));
      pbb.q = make_uint4(cvtpk(pB[2*m][0], pB[2*m][1]),   cvtpk(pB[2*m][2], pB[2*m][3]),
                         cvtpk(pB[2*m+1][0], pB[2*m+1][1]), cvtpk(pB[2*m+1][2], pB[2*m+1][3]));
#pragma unroll
      for (int dt = 0; dt < 2; ++dt) {
        oaccA[dt] = __builtin_amdgcn_mfma_f32_16x16x32_bf16(av[m][dt].v, pba.v, oaccA[dt], 0, 0, 0);
        oaccB[dt] = __builtin_amdgcn_mfma_f32_16x16x32_bf16(av[m][dt].v, pbb.v, oaccB[dt], 0, 0, 0);
      }
    }
    __builtin_amdgcn_s_setprio(0);
  }
  // ---- reduce l across the 4 l4-lanes of each q (consistent scaling) ----
  lA += __shfl_xor(lA, 16);  lA += __shfl_xor(lA, 32);
  lB += __shfl_xor(lB, 16);  lB += __shfl_xor(lB, 32);
  // ---- write partials, merge in LDS ----
#pragma unroll
  for (int dt = 0; dt < 2; ++dt)
#pragma unroll
    for (int r = 0; r < 4; ++r) {
      sO[w][ln15][dt * 16 + l4 * 4 + r]      = oaccA[dt][r];
      sO[w][16 + ln15][dt * 16 + l4 * 4 + r] = oaccB[dt][r];
    }
  if (l4 == 0) {
    sM[w][ln15] = mA; sL[w][ln15] = lA;
    sM[w][16 + ln15] = mB; sL[w][16 + ln15] = lB;
  }
  __syncthreads();
#pragma unroll
  for (int i = t; i < 1024; i += 256) {
    const int row = i >> 5, col = i & 31;
    const float M = fmaxf(fmaxf(sM[0][row], sM[1][row]), fmaxf(sM[2][row], sM[3][row]));
    float l = 0.f, O = 0.f;
#pragma unroll
    for (int w4 = 0; w4 < 4; ++w4) {
      const float sc = __builtin_amdgcn_exp2f(sM[w4][row] - M);
      l += sc * sL[w4][row];
      O += sc * sO[w4][row][col];
    }
    const int q = q0 + row;
    if (q < LQ)
      Ow[((size_t)q * BB + b) * CC + h * 32 + col] = f2bf(O / l);
  }
}

// ============================================================
// Grid-sample (R0-R4 proven version).
// ============================================================
__global__ __launch_bounds__(256) void samp_k(
    const void* __restrict__ feat, const float* __restrict__ uv,
    u16* __restrict__ S, const int* __restrict__ flag)
{
  const int df = flag[0];
  const int c = blockIdx.x;
  const int b = blockIdx.y / 5;
  const int ch = blockIdx.y % 5;
  const int qend = min((ch + 1) * 500, LQ);
  for (int q = ch * 500 + threadIdx.x; q < qend; q += 256) {
    float acc = 0.f;
#pragma unroll
    for (int cam = 0; cam < NCC; ++cam) {
      const int bc = b * NCC + cam;
      const float x = uv[((size_t)bc * LQ + q) * 2 + 0];
      const float y = uv[((size_t)bc * LQ + q) * 2 + 1];
      const float xf = floorf(x), yf = floorf(y);
      const int x0 = (int)xf, y0 = (int)yf;
      const float wx = x - xf, wy = y - yf;
      const size_t base = ((size_t)bc * CC + c) * (HFF * WFF);
      const bool vx0 = (x0 >= 0) & (x0 < WFF);
      const bool vx1 = (x0 + 1 >= 0) & (x0 + 1 < WFF);
      const bool vy0 = (y0 >= 0) & (y0 < HFF);
      const bool vy1 = (y0 + 1 >= 0) & (y0 + 1 < HFF);
      if (vy0) {
        const size_t rb = base + (size_t)y0 * WFF;
        if (vx0) acc += (1.f - wx) * (1.f - wy) * ldf1(feat, rb + x0, df);
        if (vx1) acc += wx * (1.f - wy) * ldf1(feat, rb + x0 + 1, df);
      }
      if (vy1) {
        const size_t rb = base + (size_t)(y0 + 1) * WFF;
        if (vx0) acc += (1.f - wx) * wy * ldf1(feat, rb + x0, df);
        if (vx1) acc += wx * wy * ldf1(feat, rb + x0 + 1, df);
      }
    }
    S[((size_t)q * BB + b) * CC + c] = f2bf(acc * (1.f / 6.f));
  }
}

// ============================================================
extern "C" void kernel_launch(void* const* d_in, const int* in_sizes, int n_in,
                              void* d_out, int out_size, void* d_ws, size_t ws_size,
                              hipStream_t stream) {
  (void)in_sizes; (void)n_in; (void)out_size; (void)ws_size;
  char* base = (char*)d_ws;
  int* flag = (int*)base;
  float* UV = (float*)(base + WB_UV);
  u16* WQKV = (u16*)(base + WB_WQKV);
  u16* WOP  = (u16*)(base + WB_WOP);
  u16* WSC  = (u16*)(base + WB_WSC);
  u16* WF1  = (u16*)(base + WB_WF1);
  u16* WF2  = (u16*)(base + WB_WF2);
  u16* S1 = (u16*)(base + WB_S1);
  u16* S2 = (u16*)(base + WB_S2);
  u16* S3 = (u16*)(base + WB_S3);
  u16* VT = (u16*)(base + WB_VT);
  u16* H  = (u16*)(base + WB_H);

  detect_k<<<1, 64, 0, stream>>>((const u16*)d_in[3], flag);

  WDesc wd;
  wd.src[0] = d_in[7];  wd.dst[0] = WQKV; wd.n[0] = 49152;  wd.mode[0] = 3; wd.Kd[0] = 0;    wd.Nd[0] = 0;
  wd.src[1] = d_in[9];  wd.dst[1] = WOP;  wd.n[1] = 16384;  wd.mode[1] = 3; wd.Kd[1] = 0;    wd.Nd[1] = 0;
  wd.src[2] = d_in[13]; wd.dst[2] = WSC;  wd.n[2] = 16384;  wd.mode[2] = 3; wd.Kd[2] = 0;    wd.Nd[2] = 0;
  wd.src[3] = d_in[17]; wd.dst[3] = WF1;  wd.n[3] = 262144; wd.mode[3] = 1; wd.Kd[3] = 256;  wd.Nd[3] = 1024;
  wd.src[4] = d_in[19]; wd.dst[4] = WF2;  wd.n[4] = 262144; wd.mode[4] = 1; wd.Kd[4] = 1024; wd.Nd[4] = 256;
  wd.src[5] = nullptr;  wd.dst[5] = VT;   wd.n[5] = 512 * (LQP - LQ); wd.mode[5] = 2; wd.Kd[5] = 0; wd.Nd[5] = 0;
  cvtw_k<<<dim3(128, 7), 256, 0, stream>>>(wd, d_in[3], d_in[4], d_in[5], UV, flag);

  // Fused QKV projections: Q->S1, K->S2, V->VT (transposed + permuted store)
  gemm_qkv<<<dim3(313, 12), 64, 0, stream>>>(d_in[0], d_in[1], WQKV, d_in[8], S1, S2, VT, flag);

  attn_mf<<<dim3(79, 16), 256, 0, stream>>>(S1, S2, VT, S3);

  // out-proj (+bevq residual) + LN1 -> S2
  gemm_ln<256,2,0><<<313, 256, 0, stream>>>(S3, WOP, d_in[10], d_in[0], d_in[11], d_in[12], S2, MROWS, flag);

  // sampling -> VT slot (dead after attn)
  samp_k<<<dim3(CC, BB * 5), 256, 0, stream>>>(d_in[2], UV, VT, flag);

  // SCA (+S2 residual) + LN2 -> S1
  gemm_ln<256,1,0><<<313, 256, 0, stream>>>(VT, WSC, d_in[14], S2, d_in[15], d_in[16], S1, MROWS, flag);

  // FFN: gelu(S1 @ W1 + b1) -> H ; (H @ W2 + b2 + S1) + LN3 -> out
  gemm_nl<256,1,4><<<dim3(313, 16), 64, 0, stream>>>(S1, WF1, d_in[18], H, MROWS, DFF, flag);
  gemm_ln<1024,1,1><<<313, 256, 0, stream>>>(H, WF2, d_in[20], S1, d_in[21], d_in[22], d_out, MROWS, flag);
}